// Round 1
// baseline (351.984 us; speedup 1.0000x reference)
//
#include <hip/hip_runtime.h>
#include <stdint.h>

#define D_EMB 100
#define NSYM 100001           // NUM_SYMBOLS + 1 rows in symbol_emb
#define BATCH 2048
#define NNEI 200

typedef __bf16 bf16x8 __attribute__((ext_vector_type(8)));
typedef float  f32x4  __attribute__((ext_vector_type(4)));

// ---------------------------------------------------------------------------
// Kernel 1: repack gcn_w (100 x 300 fp32, row-major) into B' (304 x 128 bf16):
//   B'[col][j] = gcn_w[d][c*100 + j],  col = c*100 + d,  zero-padded.
// This is the "B^T" operand for the MFMA GEMM (rows = output cols, K inner).
// ---------------------------------------------------------------------------
__global__ __launch_bounds__(256) void prep_bp(const float* __restrict__ gcn_w,
                                               __bf16* __restrict__ Bp) {
    int idx = blockIdx.x * 256 + threadIdx.x;      // 304*128 = 38912
    if (idx >= 304 * 128) return;
    int col = idx >> 7;
    int j   = idx & 127;
    float v = 0.0f;
    if (col < 300 && j < 100) {
        int c = col / 100, d = col % 100;
        v = gcn_w[d * 300 + c * 100 + j];
    }
    Bp[idx] = (__bf16)v;
}

// ---------------------------------------------------------------------------
// Kernel 2: P = symbol_emb @ B'^T  -> (100001 x 300) bf16, stride 300.
//   M = 100032 (1563 blocks * 4 waves * 16 rows), N = 304 (19 tiles), K = 128.
// No LDS: A-frags read fp32 from global + converted to bf16; B' is 76 KB and
// stays hot in L2 across all blocks.
// ---------------------------------------------------------------------------
__global__ __launch_bounds__(256) void gemm_P(const float* __restrict__ emb,
                                              const __bf16* __restrict__ Bp,
                                              __bf16* __restrict__ P) {
    const int wave = threadIdx.x >> 6;
    const int lane = threadIdx.x & 63;
    const int m    = lane & 15;        // A row within 16-tile / D col
    const int quad = lane >> 4;        // 0..3

    const int s0   = blockIdx.x * 64 + wave * 16;   // wave-tile symbol base
    const int s    = s0 + m;
    const int srow = (s <= NSYM - 1) ? s : (NSYM - 1);   // clamp loads

    const float* rowp = emb + (size_t)srow * D_EMB;

    bf16x8 a[4];
    #pragma unroll
    for (int ks = 0; ks < 3; ++ks) {                 // k0 <= 88, full 8 valid
        const int k0 = ks * 32 + quad * 8;
        const float4 x = *(const float4*)(rowp + k0);
        const float4 y = *(const float4*)(rowp + k0 + 4);
        bf16x8 v;
        v[0]=(__bf16)x.x; v[1]=(__bf16)x.y; v[2]=(__bf16)x.z; v[3]=(__bf16)x.w;
        v[4]=(__bf16)y.x; v[5]=(__bf16)y.y; v[6]=(__bf16)y.z; v[7]=(__bf16)y.w;
        a[ks] = v;
    }
    {   // ks = 3: quad 0 -> k 96..103 (96..99 valid), quads 1..3 -> all pad
        bf16x8 v;
        #pragma unroll
        for (int i = 0; i < 8; ++i) v[i] = (__bf16)0.0f;
        if (quad == 0) {
            const float4 x = *(const float4*)(rowp + 96);
            v[0]=(__bf16)x.x; v[1]=(__bf16)x.y; v[2]=(__bf16)x.z; v[3]=(__bf16)x.w;
        }
        a[3] = v;
    }

    #pragma unroll 1
    for (int t = 0; t < 19; ++t) {                   // N tiles: cols 0..303
        const int col0 = t * 16;
        const int cn   = col0 + m;                   // B col / D col (<= 303, in-bounds of Bp)
        const __bf16* bp = Bp + (size_t)cn * 128 + quad * 8;

        f32x4 acc = {0.f, 0.f, 0.f, 0.f};
        #pragma unroll
        for (int ks = 0; ks < 4; ++ks) {
            const bf16x8 b = *(const bf16x8*)(bp + ks * 32);
            acc = __builtin_amdgcn_mfma_f32_16x16x32_bf16(a[ks], b, acc, 0, 0, 0);
        }
        #pragma unroll
        for (int r = 0; r < 4; ++r) {                // D: col = lane&15, row = quad*4+r
            const int sr = s0 + quad * 4 + r;
            if (sr <= NSYM - 1 && cn < 300)
                P[(size_t)sr * 300 + cn] = (__bf16)acc[r];
        }
    }
}

// ---------------------------------------------------------------------------
// Kernel 3: per-batch fused gather + leaky-relu + attention softmax + gate.
// One block (256 thr = 4 waves) per batch row. Wave w handles neighbors
// n = w, w+4, ...  Lane l covers d = l and d = l+64 (l < 36).
// ---------------------------------------------------------------------------
__global__ __launch_bounds__(256) void gather_attn(
        const int*    __restrict__ conn,        // (2048, 200, 4) int32
        const __bf16* __restrict__ P,           // (100001, 300) bf16
        const float*  __restrict__ emb,         // (100001, 100) fp32
        const float*  __restrict__ gcn_w_bias,
        const float*  __restrict__ gcn_b,
        const float*  __restrict__ attn_w,      // (100,)
        const float*  __restrict__ attn_bias,   // (1,)
        const float*  __restrict__ gate_w,      // (100,)
        const float*  __restrict__ gate_w_bias, // (1,)
        const float*  __restrict__ gate_b,      // (1,)
        float* __restrict__ out) {

    __shared__ __bf16 out_s[NNEI][D_EMB];   // 40 KB
    __shared__ float  logits[NNEI];
    __shared__ float  wgt[NNEI];
    __shared__ float  part[2][D_EMB];
    __shared__ float  red[128];
    __shared__ float  gsh;

    const int b = blockIdx.x;
    const int t = threadIdx.x;
    const int w = t >> 6;
    const int l = t & 63;
    const int d1 = l + 64;
    const bool has2 = d1 < D_EMB;           // l < 36

    const float bias0 = gcn_w_bias[l] + gcn_b[l];
    const float aw0   = attn_w[l];
    const float bias1 = has2 ? (gcn_w_bias[d1] + gcn_b[d1]) : 0.f;
    const float aw1   = has2 ? attn_w[d1] : 0.f;
    const float abias = attn_bias[0];

    for (int n = w; n < NNEI; n += 4) {
        const int4 ci = *(const int4*)(conn + ((size_t)b * NNEI + n) * 4);
        const size_t r0 = (size_t)ci.y * 300;          // rel   -> P[., 0:100]
        const size_t r1 = (size_t)ci.z * 300 + 100;    // ent   -> P[., 100:200]
        const size_t r2 = (size_t)ci.w * 300 + 200;    // time  -> P[., 200:300]

        float v0 = (float)P[r0 + l] + (float)P[r1 + l] + (float)P[r2 + l] + bias0;
        v0 = v0 > 0.f ? v0 : 0.01f * v0;
        out_s[n][l] = (__bf16)v0;
        float p = v0 * aw0;
        if (has2) {
            float v1 = (float)P[r0 + d1] + (float)P[r1 + d1] + (float)P[r2 + d1] + bias1;
            v1 = v1 > 0.f ? v1 : 0.01f * v1;
            out_s[n][d1] = (__bf16)v1;
            p += v1 * aw1;
        }
        #pragma unroll
        for (int off = 32; off > 0; off >>= 1) p += __shfl_down(p, off);
        if (l == 0) logits[n] = p + abias;
    }
    __syncthreads();

    // softmax over the full 200 neighbors (reference ignores num_neighbors)
    if (w == 0) {
        float vals[4];
        float mx = -1e30f;
        #pragma unroll
        for (int j = 0; j < 4; ++j) {
            const int n = l + 64 * j;
            vals[j] = (n < NNEI) ? logits[n] : -1e30f;
            mx = fmaxf(mx, vals[j]);
        }
        #pragma unroll
        for (int off = 32; off > 0; off >>= 1) mx = fmaxf(mx, __shfl_xor(mx, off));
        float s = 0.f;
        #pragma unroll
        for (int j = 0; j < 4; ++j) {
            const int n = l + 64 * j;
            if (n < NNEI) { const float e = __expf(vals[j] - mx); wgt[n] = e; s += e; }
        }
        #pragma unroll
        for (int off = 32; off > 0; off >>= 1) s += __shfl_xor(s, off);
        const float inv = 1.f / s;
        #pragma unroll
        for (int j = 0; j < 4; ++j) {
            const int n = l + 64 * j;
            if (n < NNEI) wgt[n] *= inv;
        }
    }
    __syncthreads();

    // out_attn[d] = sum_n wgt[n] * out_s[n][d] — split n-range over 2 groups
    {
        const int g  = t >> 7;          // 0 / 1
        const int dd = t & 127;
        if (dd < D_EMB) {
            float pa = 0.f;
            const int n0 = g * 100;
            for (int n = n0; n < n0 + 100; ++n) pa += wgt[n] * (float)out_s[n][dd];
            part[g][dd] = pa;
        }
    }
    __syncthreads();

    float accd = 0.f;
    if (t < D_EMB) {
        accd = part[0][t] + part[1][t];
        red[t] = accd * gate_w[t];
    } else if (t < 128) {
        red[t] = 0.f;
    }
    __syncthreads();

    if (w == 0) {
        float r = red[l] + red[l + 64];
        #pragma unroll
        for (int off = 32; off > 0; off >>= 1) r += __shfl_xor(r, off);
        if (l == 0) gsh = 1.f / (1.f + __expf(-(r + gate_w_bias[0] + gate_b[0])));
    }
    __syncthreads();

    if (t < D_EMB) {
        const int self = conn[(size_t)b * NNEI * 4];          // connections[b][0][0]
        const float se = emb[(size_t)self * D_EMB + t];
        const float g  = gsh;
        out[(size_t)b * D_EMB + t] = accd * g + se * (1.f - g);
    }
}

// Diagnostic: if workspace is too small, encode ws_size (in MB) in d_out[0].
__global__ void ws_diag(float* out, float ws_mb) { out[0] = ws_mb; }

extern "C" void kernel_launch(void* const* d_in, const int* in_sizes, int n_in,
                              void* d_out, int out_size, void* d_ws, size_t ws_size,
                              hipStream_t stream) {
    const int*   conn        = (const int*)d_in[0];
    // d_in[1] = num_neighbors — unused by the reference
    const float* emb         = (const float*)d_in[2];
    const float* gcn_w       = (const float*)d_in[3];
    const float* gcn_w_bias  = (const float*)d_in[4];
    const float* gcn_b       = (const float*)d_in[5];
    const float* attn_w      = (const float*)d_in[6];
    const float* attn_bias   = (const float*)d_in[7];
    const float* gate_w      = (const float*)d_in[8];
    const float* gate_w_bias = (const float*)d_in[9];
    const float* gate_b      = (const float*)d_in[10];
    float* out = (float*)d_out;

    const size_t P_bytes  = (size_t)NSYM * 300 * 2;                 // 60,000,600
    const size_t Bp_off   = (P_bytes + 255) & ~(size_t)255;         // 60,000,768
    const size_t need     = Bp_off + (size_t)304 * 128 * 2;         // +77,824

    if (ws_size < need) {
        ws_diag<<<1, 1, 0, stream>>>(out, (float)(ws_size / 1.0e6));
        return;
    }

    __bf16* P  = (__bf16*)d_ws;
    __bf16* Bp = (__bf16*)((char*)d_ws + Bp_off);

    prep_bp<<<(304 * 128 + 255) / 256, 256, 0, stream>>>(gcn_w, Bp);
    gemm_P<<<(NSYM + 63) / 64, 256, 0, stream>>>(emb, Bp, P);
    gather_attn<<<BATCH, 256, 0, stream>>>(conn, P, emb, gcn_w_bias, gcn_b,
                                           attn_w, attn_bias, gate_w, gate_w_bias,
                                           gate_b, out);
}

// Round 2
// 229.391 us; speedup vs baseline: 1.5344x; 1.5344x over previous
//
#include <hip/hip_runtime.h>
#include <stdint.h>

#define D_EMB 100
#define NSYM 100001           // NUM_SYMBOLS + 1 rows in symbol_emb
#define BATCH 2048
#define NNEI 200

typedef __bf16 bf16x8 __attribute__((ext_vector_type(8)));
typedef float  f32x4  __attribute__((ext_vector_type(4)));

union bf2u { uint32_t u; __bf16 h[2]; };

// ---------------------------------------------------------------------------
// Kernel 1: repack gcn_w (100 x 300 fp32, row-major) into B' (304 x 128 bf16):
//   B'[col][j] = gcn_w[d][c*100 + j],  col = c*100 + d,  zero-padded.
// ---------------------------------------------------------------------------
__global__ __launch_bounds__(256) void prep_bp(const float* __restrict__ gcn_w,
                                               __bf16* __restrict__ Bp) {
    int idx = blockIdx.x * 256 + threadIdx.x;      // 304*128 = 38912
    if (idx >= 304 * 128) return;
    int col = idx >> 7;
    int j   = idx & 127;
    float v = 0.0f;
    if (col < 300 && j < 100) {
        int c = col / 100, d = col % 100;
        v = gcn_w[d * 300 + c * 100 + j];
    }
    Bp[idx] = (__bf16)v;
}

// ---------------------------------------------------------------------------
// Kernel 2: P = symbol_emb @ B'^T -> (100001 x 300) bf16.
// Block = 256 thr = 4 waves, covers 64 symbol rows. MFMA results staged in
// LDS (64x304 bf16), then copied out as coalesced dword stores (the 64-row
// tile is a contiguous 38,400 B span of P).
// ---------------------------------------------------------------------------
__global__ __launch_bounds__(256) void gemm_P(const float* __restrict__ emb,
                                              const __bf16* __restrict__ Bp,
                                              __bf16* __restrict__ P) {
    __shared__ __bf16 Ps[64][304];                 // 38,912 B

    const int wave = threadIdx.x >> 6;
    const int lane = threadIdx.x & 63;
    const int m    = lane & 15;
    const int quad = lane >> 4;

    const int s0 = blockIdx.x * 64;
    const int sw = s0 + wave * 16;
    const int s  = sw + m;
    const int srow = (s <= NSYM - 1) ? s : (NSYM - 1);   // clamp loads

    const float* rowp = emb + (size_t)srow * D_EMB;

    bf16x8 a[4];
    #pragma unroll
    for (int ks = 0; ks < 3; ++ks) {               // k0 <= 88, full 8 valid
        const int k0 = ks * 32 + quad * 8;
        const float4 x = *(const float4*)(rowp + k0);
        const float4 y = *(const float4*)(rowp + k0 + 4);
        bf16x8 v;
        v[0]=(__bf16)x.x; v[1]=(__bf16)x.y; v[2]=(__bf16)x.z; v[3]=(__bf16)x.w;
        v[4]=(__bf16)y.x; v[5]=(__bf16)y.y; v[6]=(__bf16)y.z; v[7]=(__bf16)y.w;
        a[ks] = v;
    }
    {   // ks = 3: quad 0 -> k 96..99 valid, rest pad
        bf16x8 v;
        #pragma unroll
        for (int i = 0; i < 8; ++i) v[i] = (__bf16)0.0f;
        if (quad == 0) {
            const float4 x = *(const float4*)(rowp + 96);
            v[0]=(__bf16)x.x; v[1]=(__bf16)x.y; v[2]=(__bf16)x.z; v[3]=(__bf16)x.w;
        }
        a[3] = v;
    }

    #pragma unroll 1
    for (int t = 0; t < 19; ++t) {                 // N tiles: cols 0..303
        const int col0 = t * 16;
        const int cn   = col0 + m;
        const __bf16* bp = Bp + (size_t)cn * 128 + quad * 8;

        f32x4 acc = {0.f, 0.f, 0.f, 0.f};
        #pragma unroll
        for (int ks = 0; ks < 4; ++ks) {
            const bf16x8 b = *(const bf16x8*)(bp + ks * 32);
            acc = __builtin_amdgcn_mfma_f32_16x16x32_bf16(a[ks], b, acc, 0, 0, 0);
        }
        #pragma unroll
        for (int r = 0; r < 4; ++r)                // D: col = lane&15, row = quad*4+r
            Ps[wave * 16 + quad * 4 + r][cn] = (__bf16)acc[r];
    }
    __syncthreads();

    // Coalesced copy-out: vr valid rows, 150 dwords (300 bf16) per row.
    const int vr = (NSYM - s0 < 64) ? (NSYM - s0) : 64;
    const int total = vr * 150;
    uint32_t* __restrict__ Pd = (uint32_t*)P;
    const char* lds = (const char*)&Ps[0][0];
    for (int i = threadIdx.x; i < total; i += 256) {
        const int row = i / 150;
        const int c2  = i - row * 150;
        const uint32_t v = *(const uint32_t*)(lds + row * 608 + c2 * 4);
        Pd[(size_t)(s0 + row) * 150 + c2] = v;
    }
}

// ---------------------------------------------------------------------------
// Kernel 3: per-batch fused gather + leaky-relu + attention softmax + gate.
// One block of 1024 thr (16 waves) per batch row; LDS 48.5 KB -> 2 blocks/CU
// = 32 waves/CU (100% occupancy). conn preloaded to LDS; lane l covers
// d = 2l, 2l+1 via single 4-byte loads; loop unrolled x2 (6 loads in flight).
// ---------------------------------------------------------------------------
__global__ __launch_bounds__(1024) void gather_attn(
        const int*    __restrict__ conn,        // (2048, 200, 4) int32
        const __bf16* __restrict__ P,           // (100001, 300) bf16
        const float*  __restrict__ emb,         // (100001, 100) fp32
        const float*  __restrict__ gcn_w_bias,
        const float*  __restrict__ gcn_b,
        const float*  __restrict__ attn_w,      // (100,)
        const float*  __restrict__ attn_bias,   // (1,)
        const float*  __restrict__ gate_w,      // (100,)
        const float*  __restrict__ gate_w_bias, // (1,)
        const float*  __restrict__ gate_b,      // (1,)
        float* __restrict__ out) {

    __shared__ __bf16 out_s[NNEI][D_EMB];   // 40,000 B
    __shared__ int4   conn_s[NNEI];         //  3,200 B
    __shared__ float  logits[NNEI];
    __shared__ float  wgt[NNEI];
    __shared__ float  part[8][D_EMB];
    __shared__ float  red[128];
    __shared__ float  gsh;

    const int b = blockIdx.x;
    const int t = threadIdx.x;
    const int w = t >> 6;
    const int l = t & 63;

    if (t < NNEI) conn_s[t] = *(const int4*)(conn + ((size_t)b * NNEI + t) * 4);

    const bool act = (l < 50);
    const int  d0  = 2 * l;
    float bias0 = 0.f, bias1 = 0.f, aw0 = 0.f, aw1 = 0.f;
    if (act) {
        bias0 = gcn_w_bias[d0]     + gcn_b[d0];
        bias1 = gcn_w_bias[d0 + 1] + gcn_b[d0 + 1];
        aw0   = attn_w[d0];
        aw1   = attn_w[d0 + 1];
    }
    const float abias = attn_bias[0];
    __syncthreads();

    // Waves 0..15 cover residues w (direct) and w+16 (unrolled partner) mod 32.
    for (int n = w; n < NNEI; n += 32) {
        const int  n2 = n + 16;
        const bool g2 = (n2 < NNEI);
        const int4 ci = conn_s[n];
        const int4 cj = g2 ? conn_s[n2] : ci;

        uint32_t u0 = 0, u1 = 0, u2 = 0, x0 = 0, x1 = 0, x2 = 0;
        if (act) {
            u0 = *(const uint32_t*)(P + (size_t)ci.y * 300 +       d0);
            u1 = *(const uint32_t*)(P + (size_t)ci.z * 300 + 100 + d0);
            u2 = *(const uint32_t*)(P + (size_t)ci.w * 300 + 200 + d0);
            x0 = *(const uint32_t*)(P + (size_t)cj.y * 300 +       d0);
            x1 = *(const uint32_t*)(P + (size_t)cj.z * 300 + 100 + d0);
            x2 = *(const uint32_t*)(P + (size_t)cj.w * 300 + 200 + d0);
        }

        // neighbor n
        {
            bf2u a0, a1, a2; a0.u = u0; a1.u = u1; a2.u = u2;
            float v0 = 0.f, v1 = 0.f;
            if (act) {
                v0 = (float)a0.h[0] + (float)a1.h[0] + (float)a2.h[0] + bias0;
                v1 = (float)a0.h[1] + (float)a1.h[1] + (float)a2.h[1] + bias1;
                v0 = v0 > 0.f ? v0 : 0.01f * v0;
                v1 = v1 > 0.f ? v1 : 0.01f * v1;
                bf2u o; o.h[0] = (__bf16)v0; o.h[1] = (__bf16)v1;
                *(uint32_t*)&out_s[n][d0] = o.u;
            }
            float p = v0 * aw0 + v1 * aw1;
            #pragma unroll
            for (int off = 32; off > 0; off >>= 1) p += __shfl_down(p, off);
            if (l == 0) logits[n] = p + abias;
        }
        // neighbor n2
        if (g2) {
            bf2u a0, a1, a2; a0.u = x0; a1.u = x1; a2.u = x2;
            float v0 = 0.f, v1 = 0.f;
            if (act) {
                v0 = (float)a0.h[0] + (float)a1.h[0] + (float)a2.h[0] + bias0;
                v1 = (float)a0.h[1] + (float)a1.h[1] + (float)a2.h[1] + bias1;
                v0 = v0 > 0.f ? v0 : 0.01f * v0;
                v1 = v1 > 0.f ? v1 : 0.01f * v1;
                bf2u o; o.h[0] = (__bf16)v0; o.h[1] = (__bf16)v1;
                *(uint32_t*)&out_s[n2][d0] = o.u;
            }
            float p = v0 * aw0 + v1 * aw1;
            #pragma unroll
            for (int off = 32; off > 0; off >>= 1) p += __shfl_down(p, off);
            if (l == 0) logits[n2] = p + abias;
        }
    }
    __syncthreads();

    // softmax over all 200 neighbors (reference ignores num_neighbors)
    if (w == 0) {
        float vals[4];
        float mx = -1e30f;
        #pragma unroll
        for (int j = 0; j < 4; ++j) {
            const int n = l + 64 * j;
            vals[j] = (n < NNEI) ? logits[n] : -1e30f;
            mx = fmaxf(mx, vals[j]);
        }
        #pragma unroll
        for (int off = 32; off > 0; off >>= 1) mx = fmaxf(mx, __shfl_xor(mx, off));
        float s = 0.f;
        #pragma unroll
        for (int j = 0; j < 4; ++j) {
            const int n = l + 64 * j;
            if (n < NNEI) { const float e = __expf(vals[j] - mx); wgt[n] = e; s += e; }
        }
        #pragma unroll
        for (int off = 32; off > 0; off >>= 1) s += __shfl_xor(s, off);
        const float inv = 1.f / s;
        #pragma unroll
        for (int j = 0; j < 4; ++j) {
            const int n = l + 64 * j;
            if (n < NNEI) wgt[n] *= inv;
        }
    }
    __syncthreads();

    // out_attn[d] = sum_n wgt[n]*out_s[n][d] — 8 groups of 128 thr, 25 n each
    {
        const int g  = t >> 7;
        const int dd = t & 127;
        if (dd < D_EMB) {
            float pa = 0.f;
            const int n0 = g * 25;
            #pragma unroll 5
            for (int n = n0; n < n0 + 25; ++n) pa += wgt[n] * (float)out_s[n][dd];
            part[g][dd] = pa;
        }
    }
    __syncthreads();

    float accd = 0.f;
    if (t < D_EMB) {
        #pragma unroll
        for (int g = 0; g < 8; ++g) accd += part[g][t];
        red[t] = accd * gate_w[t];
    } else if (t < 128) {
        red[t] = 0.f;
    }
    __syncthreads();

    if (w == 0) {
        float r = red[l] + red[l + 64];
        #pragma unroll
        for (int off = 32; off > 0; off >>= 1) r += __shfl_xor(r, off);
        if (l == 0) gsh = 1.f / (1.f + __expf(-(r + gate_w_bias[0] + gate_b[0])));
    }
    __syncthreads();

    if (t < D_EMB) {
        const int self = conn_s[0].x;              // connections[b][0][0]
        const float se = emb[(size_t)self * D_EMB + t];
        const float g  = gsh;
        out[(size_t)b * D_EMB + t] = accd * g + se * (1.f - g);
    }
}

// Diagnostic: if workspace is too small, encode ws_size (in MB) in d_out[0].
__global__ void ws_diag(float* out, float ws_mb) { out[0] = ws_mb; }

extern "C" void kernel_launch(void* const* d_in, const int* in_sizes, int n_in,
                              void* d_out, int out_size, void* d_ws, size_t ws_size,
                              hipStream_t stream) {
    const int*   conn        = (const int*)d_in[0];
    // d_in[1] = num_neighbors — unused by the reference
    const float* emb         = (const float*)d_in[2];
    const float* gcn_w       = (const float*)d_in[3];
    const float* gcn_w_bias  = (const float*)d_in[4];
    const float* gcn_b       = (const float*)d_in[5];
    const float* attn_w      = (const float*)d_in[6];
    const float* attn_bias   = (const float*)d_in[7];
    const float* gate_w      = (const float*)d_in[8];
    const float* gate_w_bias = (const float*)d_in[9];
    const float* gate_b      = (const float*)d_in[10];
    float* out = (float*)d_out;

    const size_t P_bytes  = (size_t)NSYM * 300 * 2;                 // 60,000,600
    const size_t Bp_off   = (P_bytes + 255) & ~(size_t)255;
    const size_t need     = Bp_off + (size_t)304 * 128 * 2;

    if (ws_size < need) {
        ws_diag<<<1, 1, 0, stream>>>(out, (float)(ws_size / 1.0e6));
        return;
    }

    __bf16* P  = (__bf16*)d_ws;
    __bf16* Bp = (__bf16*)((char*)d_ws + Bp_off);

    prep_bp<<<(304 * 128 + 255) / 256, 256, 0, stream>>>(gcn_w, Bp);
    gemm_P<<<(NSYM + 63) / 64, 256, 0, stream>>>(emb, Bp, P);
    gather_attn<<<BATCH, 1024, 0, stream>>>(conn, P, emb, gcn_w_bias, gcn_b,
                                            attn_w, attn_bias, gate_w, gate_w_bias,
                                            gate_b, out);
}

// Round 3
// 225.193 us; speedup vs baseline: 1.5630x; 1.0186x over previous
//
#include <hip/hip_runtime.h>
#include <stdint.h>

#define D_EMB 100
#define NSYM 100001           // NUM_SYMBOLS + 1 rows in symbol_emb
#define BATCH 2048
#define NNEI 200

typedef __bf16 bf16x8 __attribute__((ext_vector_type(8)));
typedef __bf16 bf16x4 __attribute__((ext_vector_type(4)));
typedef float  f32x4  __attribute__((ext_vector_type(4)));

union bf2u { uint32_t u; __bf16 h[2]; };

// ---------------------------------------------------------------------------
// Kernel 1: repack gcn_w (100 x 300 fp32, row-major) into B' (304 x 128 bf16):
//   B'[col][j] = gcn_w[d][c*100 + j],  col = c*100 + d,  zero-padded.
// ---------------------------------------------------------------------------
__global__ __launch_bounds__(256) void prep_bp(const float* __restrict__ gcn_w,
                                               __bf16* __restrict__ Bp) {
    int idx = blockIdx.x * 256 + threadIdx.x;      // 304*128 = 38912
    if (idx >= 304 * 128) return;
    int col = idx >> 7;
    int j   = idx & 127;
    float v = 0.0f;
    if (col < 300 && j < 100) {
        int c = col / 100, d = col % 100;
        v = gcn_w[d * 300 + c * 100 + j];
    }
    Bp[idx] = (__bf16)v;
}

// ---------------------------------------------------------------------------
// Kernel 2: P = symbol_emb @ B'^T -> (100001 x 300) bf16.
// OPERAND-SWAPPED MFMA: D = Bp_tile (A) x emb_tile (B), so
//   D col = lane&15 = symbol, D row = quad*4+r = P-column.
// Each lane packs 4 consecutive P-columns into one 8-byte store.
// No LDS, no barrier -> 8 blocks/CU (wave-cap occupancy), zero bank conflicts.
// ---------------------------------------------------------------------------
__global__ __launch_bounds__(256) void gemm_P(const float* __restrict__ emb,
                                              const __bf16* __restrict__ Bp,
                                              __bf16* __restrict__ P) {
    const int wave = threadIdx.x >> 6;
    const int lane = threadIdx.x & 63;
    const int n    = lane & 15;        // symbol within wave-tile (non-K index)
    const int quad = lane >> 4;

    const int s0w  = blockIdx.x * 64 + wave * 16;
    const int s    = s0w + n;
    const int srow = (s <= NSYM - 1) ? s : (NSYM - 1);   // clamp loads

    const float* rowp = emb + (size_t)srow * D_EMB;

    // B operand: this lane's symbol row, K = 128 (100 valid + pad)
    bf16x8 b[4];
    #pragma unroll
    for (int ks = 0; ks < 3; ++ks) {               // k0 <= 88, full 8 valid
        const int k0 = ks * 32 + quad * 8;
        const float4 x = *(const float4*)(rowp + k0);
        const float4 y = *(const float4*)(rowp + k0 + 4);
        bf16x8 v;
        v[0]=(__bf16)x.x; v[1]=(__bf16)x.y; v[2]=(__bf16)x.z; v[3]=(__bf16)x.w;
        v[4]=(__bf16)y.x; v[5]=(__bf16)y.y; v[6]=(__bf16)y.z; v[7]=(__bf16)y.w;
        b[ks] = v;
    }
    {   // ks = 3: quad 0 -> k 96..99 valid, rest pad
        bf16x8 v;
        #pragma unroll
        for (int i = 0; i < 8; ++i) v[i] = (__bf16)0.0f;
        if (quad == 0) {
            const float4 x = *(const float4*)(rowp + 96);
            v[0]=(__bf16)x.x; v[1]=(__bf16)x.y; v[2]=(__bf16)x.z; v[3]=(__bf16)x.w;
        }
        b[3] = v;
    }

    const bool   wr   = (s <= NSYM - 1);
    __bf16* __restrict__ orow = P + (size_t)s * 300 + quad * 4;
    const __bf16* __restrict__ apBase = Bp + (size_t)n * 128 + quad * 8;

    for (int t = 0; t < 19; ++t) {                 // P-column tiles 0..303
        const __bf16* ap = apBase + (size_t)t * 16 * 128;

        f32x4 acc = {0.f, 0.f, 0.f, 0.f};
        #pragma unroll
        for (int ks = 0; ks < 4; ++ks) {
            const bf16x8 a = *(const bf16x8*)(ap + ks * 32);
            acc = __builtin_amdgcn_mfma_f32_16x16x32_bf16(a, b[ks], acc, 0, 0, 0);
        }
        // D row = quad*4+r = P column (t*16 + quad*4 + r), D col = symbol s
        if (wr && (t < 18 || quad < 3)) {          // tile 18 quad 3 = pad cols
            bf16x4 o;
            o[0] = (__bf16)acc[0]; o[1] = (__bf16)acc[1];
            o[2] = (__bf16)acc[2]; o[3] = (__bf16)acc[3];
            *(bf16x4*)(orow + t * 16) = o;
        }
    }
}

// ---------------------------------------------------------------------------
// Kernel 3: per-batch fused gather + leaky-relu + attention softmax + gate.
// One block of 1024 thr (16 waves) per batch row; LDS 48.5 KB -> 2 blocks/CU
// = 32 waves/CU. conn preloaded to LDS; lane l covers d = 2l, 2l+1 via single
// 4-byte loads; loop unrolled x2 (6 loads in flight).
// ---------------------------------------------------------------------------
__global__ __launch_bounds__(1024) void gather_attn(
        const int*    __restrict__ conn,        // (2048, 200, 4) int32
        const __bf16* __restrict__ P,           // (100001, 300) bf16
        const float*  __restrict__ emb,         // (100001, 100) fp32
        const float*  __restrict__ gcn_w_bias,
        const float*  __restrict__ gcn_b,
        const float*  __restrict__ attn_w,      // (100,)
        const float*  __restrict__ attn_bias,   // (1,)
        const float*  __restrict__ gate_w,      // (100,)
        const float*  __restrict__ gate_w_bias, // (1,)
        const float*  __restrict__ gate_b,      // (1,)
        float* __restrict__ out) {

    __shared__ __bf16 out_s[NNEI][D_EMB];   // 40,000 B
    __shared__ int4   conn_s[NNEI];         //  3,200 B
    __shared__ float  logits[NNEI];
    __shared__ float  wgt[NNEI];
    __shared__ float  part[8][D_EMB];
    __shared__ float  red[128];
    __shared__ float  gsh;

    const int b = blockIdx.x;
    const int t = threadIdx.x;
    const int w = t >> 6;
    const int l = t & 63;

    if (t < NNEI) conn_s[t] = *(const int4*)(conn + ((size_t)b * NNEI + t) * 4);

    const bool act = (l < 50);
    const int  d0  = 2 * l;
    float bias0 = 0.f, bias1 = 0.f, aw0 = 0.f, aw1 = 0.f;
    if (act) {
        bias0 = gcn_w_bias[d0]     + gcn_b[d0];
        bias1 = gcn_w_bias[d0 + 1] + gcn_b[d0 + 1];
        aw0   = attn_w[d0];
        aw1   = attn_w[d0 + 1];
    }
    const float abias = attn_bias[0];
    __syncthreads();

    // Waves 0..15 cover residues w (direct) and w+16 (unrolled partner) mod 32.
    for (int n = w; n < NNEI; n += 32) {
        const int  n2 = n + 16;
        const bool g2 = (n2 < NNEI);
        const int4 ci = conn_s[n];
        const int4 cj = g2 ? conn_s[n2] : ci;

        uint32_t u0 = 0, u1 = 0, u2 = 0, x0 = 0, x1 = 0, x2 = 0;
        if (act) {
            u0 = *(const uint32_t*)(P + (size_t)ci.y * 300 +       d0);
            u1 = *(const uint32_t*)(P + (size_t)ci.z * 300 + 100 + d0);
            u2 = *(const uint32_t*)(P + (size_t)ci.w * 300 + 200 + d0);
            x0 = *(const uint32_t*)(P + (size_t)cj.y * 300 +       d0);
            x1 = *(const uint32_t*)(P + (size_t)cj.z * 300 + 100 + d0);
            x2 = *(const uint32_t*)(P + (size_t)cj.w * 300 + 200 + d0);
        }

        // neighbor n
        {
            bf2u a0, a1, a2; a0.u = u0; a1.u = u1; a2.u = u2;
            float v0 = 0.f, v1 = 0.f;
            if (act) {
                v0 = (float)a0.h[0] + (float)a1.h[0] + (float)a2.h[0] + bias0;
                v1 = (float)a0.h[1] + (float)a1.h[1] + (float)a2.h[1] + bias1;
                v0 = v0 > 0.f ? v0 : 0.01f * v0;
                v1 = v1 > 0.f ? v1 : 0.01f * v1;
                bf2u o; o.h[0] = (__bf16)v0; o.h[1] = (__bf16)v1;
                *(uint32_t*)&out_s[n][d0] = o.u;
            }
            float p = v0 * aw0 + v1 * aw1;
            #pragma unroll
            for (int off = 32; off > 0; off >>= 1) p += __shfl_down(p, off);
            if (l == 0) logits[n] = p + abias;
        }
        // neighbor n2
        if (g2) {
            bf2u a0, a1, a2; a0.u = x0; a1.u = x1; a2.u = x2;
            float v0 = 0.f, v1 = 0.f;
            if (act) {
                v0 = (float)a0.h[0] + (float)a1.h[0] + (float)a2.h[0] + bias0;
                v1 = (float)a0.h[1] + (float)a1.h[1] + (float)a2.h[1] + bias1;
                v0 = v0 > 0.f ? v0 : 0.01f * v0;
                v1 = v1 > 0.f ? v1 : 0.01f * v1;
                bf2u o; o.h[0] = (__bf16)v0; o.h[1] = (__bf16)v1;
                *(uint32_t*)&out_s[n2][d0] = o.u;
            }
            float p = v0 * aw0 + v1 * aw1;
            #pragma unroll
            for (int off = 32; off > 0; off >>= 1) p += __shfl_down(p, off);
            if (l == 0) logits[n2] = p + abias;
        }
    }
    __syncthreads();

    // softmax over all 200 neighbors (reference ignores num_neighbors)
    if (w == 0) {
        float vals[4];
        float mx = -1e30f;
        #pragma unroll
        for (int j = 0; j < 4; ++j) {
            const int n = l + 64 * j;
            vals[j] = (n < NNEI) ? logits[n] : -1e30f;
            mx = fmaxf(mx, vals[j]);
        }
        #pragma unroll
        for (int off = 32; off > 0; off >>= 1) mx = fmaxf(mx, __shfl_xor(mx, off));
        float s = 0.f;
        #pragma unroll
        for (int j = 0; j < 4; ++j) {
            const int n = l + 64 * j;
            if (n < NNEI) { const float e = __expf(vals[j] - mx); wgt[n] = e; s += e; }
        }
        #pragma unroll
        for (int off = 32; off > 0; off >>= 1) s += __shfl_xor(s, off);
        const float inv = 1.f / s;
        #pragma unroll
        for (int j = 0; j < 4; ++j) {
            const int n = l + 64 * j;
            if (n < NNEI) wgt[n] *= inv;
        }
    }
    __syncthreads();

    // out_attn[d] = sum_n wgt[n]*out_s[n][d] — 8 groups of 128 thr, 25 n each
    {
        const int g  = t >> 7;
        const int dd = t & 127;
        if (dd < D_EMB) {
            float pa = 0.f;
            const int n0 = g * 25;
            #pragma unroll 5
            for (int n = n0; n < n0 + 25; ++n) pa += wgt[n] * (float)out_s[n][dd];
            part[g][dd] = pa;
        }
    }
    __syncthreads();

    float accd = 0.f;
    if (t < D_EMB) {
        #pragma unroll
        for (int g = 0; g < 8; ++g) accd += part[g][t];
        red[t] = accd * gate_w[t];
    } else if (t < 128) {
        red[t] = 0.f;
    }
    __syncthreads();

    if (w == 0) {
        float r = red[l] + red[l + 64];
        #pragma unroll
        for (int off = 32; off > 0; off >>= 1) r += __shfl_xor(r, off);
        if (l == 0) gsh = 1.f / (1.f + __expf(-(r + gate_w_bias[0] + gate_b[0])));
    }
    __syncthreads();

    if (t < D_EMB) {
        const int self = conn_s[0].x;              // connections[b][0][0]
        const float se = emb[(size_t)self * D_EMB + t];
        const float g  = gsh;
        out[(size_t)b * D_EMB + t] = accd * g + se * (1.f - g);
    }
}

// Diagnostic: if workspace is too small, encode ws_size (in MB) in d_out[0].
__global__ void ws_diag(float* out, float ws_mb) { out[0] = ws_mb; }

extern "C" void kernel_launch(void* const* d_in, const int* in_sizes, int n_in,
                              void* d_out, int out_size, void* d_ws, size_t ws_size,
                              hipStream_t stream) {
    const int*   conn        = (const int*)d_in[0];
    // d_in[1] = num_neighbors — unused by the reference
    const float* emb         = (const float*)d_in[2];
    const float* gcn_w       = (const float*)d_in[3];
    const float* gcn_w_bias  = (const float*)d_in[4];
    const float* gcn_b       = (const float*)d_in[5];
    const float* attn_w      = (const float*)d_in[6];
    const float* attn_bias   = (const float*)d_in[7];
    const float* gate_w      = (const float*)d_in[8];
    const float* gate_w_bias = (const float*)d_in[9];
    const float* gate_b      = (const float*)d_in[10];
    float* out = (float*)d_out;

    const size_t P_bytes  = (size_t)NSYM * 300 * 2;                 // 60,000,600
    const size_t Bp_off   = (P_bytes + 255) & ~(size_t)255;
    const size_t need     = Bp_off + (size_t)304 * 128 * 2;

    if (ws_size < need) {
        ws_diag<<<1, 1, 0, stream>>>(out, (float)(ws_size / 1.0e6));
        return;
    }

    __bf16* P  = (__bf16*)d_ws;
    __bf16* Bp = (__bf16*)((char*)d_ws + Bp_off);

    prep_bp<<<(304 * 128 + 255) / 256, 256, 0, stream>>>(gcn_w, Bp);
    gemm_P<<<(NSYM + 63) / 64, 256, 0, stream>>>(emb, Bp, P);
    gather_attn<<<BATCH, 1024, 0, stream>>>(conn, P, emb, gcn_w_bias, gcn_b,
                                            attn_w, attn_bias, gate_w, gate_w_bias,
                                            gate_b, out);
}

// Round 4
// 198.948 us; speedup vs baseline: 1.7692x; 1.1319x over previous
//
#include <hip/hip_runtime.h>
#include <stdint.h>

#define D_EMB 100
#define NSYM 100001           // NUM_SYMBOLS + 1 rows in symbol_emb
#define BATCH 2048
#define NNEI 200

#define BP_ELEMS   32000      // packed Bp: 20 tiles x (3ks x 4q x 16n x 8 + 16n x 4)
#define BP_KS3_OFF 30720      // start of the dense ks=3 region

typedef __bf16 bf16x8 __attribute__((ext_vector_type(8)));
typedef __bf16 bf16x4 __attribute__((ext_vector_type(4)));
typedef float  f32x4  __attribute__((ext_vector_type(4)));
// reduced-alignment vector types for 8-B-aligned global stores (gfx9+ allows)
typedef bf16x8 bf16x8_a8 __attribute__((aligned(8)));
typedef bf16x4 bf16x4_a8 __attribute__((aligned(8)));

union bf2u { uint32_t u; __bf16 h[2]; };

// col covered by (tile tau, A-row n): paired-tile permutation so that
// lane quad's acc(tile 2u) ++ acc(tile 2u+1) = 8 consecutive P-columns.
__host__ __device__ inline int colmap(int tau, int n) {
    return 32 * (tau >> 1) + 8 * (n >> 2) + 4 * (tau & 1) + (n & 3);
}

// ---------------------------------------------------------------------------
// Kernel 1: repack gcn_w (100 x 300 fp32) into packed fragment-ordered Bp.
// Region A (idx < 30720): idx = ((tau*12 + ks*4 + q)*16 + n)*8 + j,
//   holds W'[col(tau,n), k = ks*32 + q*8 + j]   (ks = 0..2)
// Region B (idx >= 30720): i2 = tau*64 + n*4 + j, holds k = 96 + j.
//   W'[col, k] = gcn_w[col%100][ (col/100)*100 + k ]
// ---------------------------------------------------------------------------
__global__ __launch_bounds__(256) void prep_bp(const float* __restrict__ gcn_w,
                                               __bf16* __restrict__ Bp) {
    int idx = blockIdx.x * 256 + threadIdx.x;
    if (idx >= BP_ELEMS) return;
    int tau, n, k;
    if (idx < BP_KS3_OFF) {
        int j = idx & 7;
        n     = (idx >> 3) & 15;
        int z = idx >> 7;            // tau*12 + ks*4 + q
        tau   = z / 12;
        int r = z - tau * 12;
        int ks = r >> 2, q = r & 3;
        k = ks * 32 + q * 8 + j;
    } else {
        int i2 = idx - BP_KS3_OFF;
        int j  = i2 & 3;
        n      = (i2 >> 2) & 15;
        tau    = i2 >> 6;
        k      = 96 + j;
    }
    const int col = colmap(tau, n);
    float v = 0.0f;
    if (col < 300 && k < 100) {
        int c = col / 100, d = col % 100;
        v = gcn_w[d * 300 + c * 100 + k];
    }
    Bp[idx] = (__bf16)v;
}

// ---------------------------------------------------------------------------
// Kernel 2: P = symbol_emb @ W'^T -> (100001 x 300) bf16.
// Block = 256 thr (4 waves, 64 symbols). Bp staged in LDS once per block
// (64,016 B -> 2 blocks/CU). Operand-swapped MFMA (A = Bp frag from LDS,
// B = emb frag in regs). Paired tiles -> one 16-B store per lane per pair.
// LDS layout is fragment-ordered: ds_read_b128 is conflict-free (8/bank).
// ---------------------------------------------------------------------------
__global__ __launch_bounds__(256) void gemm_P(const float* __restrict__ emb,
                                              const __bf16* __restrict__ Bp,
                                              __bf16* __restrict__ P) {
    __shared__ __bf16 BpS[BP_ELEMS + 8];     // + 8-elem zero slot

    const int tid  = threadIdx.x;
    const int wave = tid >> 6;
    const int lane = tid & 63;
    const int n    = lane & 15;
    const int quad = lane >> 4;

    // ---- stage packed Bp into LDS (64,000 B contiguous, coalesced) ----
    {
        const uint4* __restrict__ src = (const uint4*)Bp;
        uint4* dst = (uint4*)BpS;
        for (int c = tid; c < BP_ELEMS / 8; c += 256)    // 4000 x 16 B
            dst[c] = src[c];
        if (tid < 8) BpS[BP_ELEMS + tid] = (__bf16)0.0f; // zero slot
    }

    // ---- emb fragments (B operand) for this wave's 16 symbols ----
    const int sBase = blockIdx.x * 64 + wave * 16;
    const int s     = sBase + n;
    const int srow  = (s <= NSYM - 1) ? s : (NSYM - 1);  // clamp loads
    const float* rowp = emb + (size_t)srow * D_EMB;

    bf16x8 b[4];
    #pragma unroll
    for (int ks = 0; ks < 3; ++ks) {                     // k0 <= 88
        const int k0 = ks * 32 + quad * 8;
        const float4 x = *(const float4*)(rowp + k0);
        const float4 y = *(const float4*)(rowp + k0 + 4);
        bf16x8 v;
        v[0]=(__bf16)x.x; v[1]=(__bf16)x.y; v[2]=(__bf16)x.z; v[3]=(__bf16)x.w;
        v[4]=(__bf16)y.x; v[5]=(__bf16)y.y; v[6]=(__bf16)y.z; v[7]=(__bf16)y.w;
        b[ks] = v;
    }
    {   // ks = 3: only quad 0 / k 96..99 nonzero
        bf16x8 v;
        #pragma unroll
        for (int i = 0; i < 8; ++i) v[i] = (__bf16)0.0f;
        if (quad == 0) {
            const float4 x = *(const float4*)(rowp + 96);
            v[0]=(__bf16)x.x; v[1]=(__bf16)x.y; v[2]=(__bf16)x.z; v[3]=(__bf16)x.w;
        }
        b[3] = v;
    }

    __syncthreads();

    const bool wr = (s <= NSYM - 1);
    __bf16* __restrict__ prow = P + (size_t)s * 300;

    for (int u = 0; u < 10; ++u) {
        const int t0 = 2 * u, t1 = t0 + 1;

        bf16x8 a0[4], a1[4];
        #pragma unroll
        for (int ks = 0; ks < 3; ++ks) {
            a0[ks] = *(const bf16x8*)&BpS[((t0 * 12 + ks * 4 + quad) * 16 + n) * 8];
            a1[ks] = *(const bf16x8*)&BpS[((t1 * 12 + ks * 4 + quad) * 16 + n) * 8];
        }
        {   // ks = 3: quad 0 reads dense 4-elem chunk; others read zero slot
            const int o0 = (quad == 0) ? (BP_KS3_OFF + (t0 * 16 + n) * 4) : BP_ELEMS;
            const int o1 = (quad == 0) ? (BP_KS3_OFF + (t1 * 16 + n) * 4) : BP_ELEMS;
            const bf16x4 w0 = *(const bf16x4*)&BpS[o0];
            const bf16x4 w1 = *(const bf16x4*)&BpS[o1];
            bf16x8 v0, v1;
            #pragma unroll
            for (int i = 0; i < 4; ++i) {
                v0[i] = w0[i]; v1[i] = w1[i];
                v0[i + 4] = (__bf16)0.0f; v1[i + 4] = (__bf16)0.0f;
            }
            a0[3] = v0; a1[3] = v1;
        }

        f32x4 acc0 = {0.f, 0.f, 0.f, 0.f};
        f32x4 acc1 = {0.f, 0.f, 0.f, 0.f};
        #pragma unroll
        for (int ks = 0; ks < 4; ++ks) {
            acc0 = __builtin_amdgcn_mfma_f32_16x16x32_bf16(a0[ks], b[ks], acc0, 0, 0, 0);
            acc1 = __builtin_amdgcn_mfma_f32_16x16x32_bf16(a1[ks], b[ks], acc1, 0, 0, 0);
        }

        // lane (n, quad): symbol s, cols 32u + 8*quad + {0..7} (acc0 | acc1)
        if (wr) {
            const int colBase = 32 * u + 8 * quad;
            if (colBase + 8 <= 300) {
                bf16x8_a8 o;
                o[0]=(__bf16)acc0[0]; o[1]=(__bf16)acc0[1];
                o[2]=(__bf16)acc0[2]; o[3]=(__bf16)acc0[3];
                o[4]=(__bf16)acc1[0]; o[5]=(__bf16)acc1[1];
                o[6]=(__bf16)acc1[2]; o[7]=(__bf16)acc1[3];
                *(bf16x8_a8*)(prow + colBase) = o;
            } else if (colBase + 4 <= 300) {           // u=9, quad=1: 296..299
                bf16x4_a8 o;
                o[0]=(__bf16)acc0[0]; o[1]=(__bf16)acc0[1];
                o[2]=(__bf16)acc0[2]; o[3]=(__bf16)acc0[3];
                *(bf16x4_a8*)(prow + colBase) = o;
            }
        }
    }
}

// ---------------------------------------------------------------------------
// Kernel 3: per-batch fused gather + leaky-relu + attention softmax + gate.
// 1024 thr (16 waves) per batch row, 2 blocks/CU. 4-neighbor unroll:
// 12 independent P-row loads in flight per wave iteration.
// ---------------------------------------------------------------------------
__global__ __launch_bounds__(1024) void gather_attn(
        const int*    __restrict__ conn,        // (2048, 200, 4) int32
        const __bf16* __restrict__ P,           // (100001, 300) bf16
        const float*  __restrict__ emb,         // (100001, 100) fp32
        const float*  __restrict__ gcn_w_bias,
        const float*  __restrict__ gcn_b,
        const float*  __restrict__ attn_w,      // (100,)
        const float*  __restrict__ attn_bias,   // (1,)
        const float*  __restrict__ gate_w,      // (100,)
        const float*  __restrict__ gate_w_bias, // (1,)
        const float*  __restrict__ gate_b,      // (1,)
        float* __restrict__ out) {

    __shared__ __bf16 out_s[NNEI][D_EMB];   // 40,000 B
    __shared__ int4   conn_s[NNEI];         //  3,200 B
    __shared__ float  logits[NNEI];
    __shared__ float  wgt[NNEI];
    __shared__ float  part[8][D_EMB];
    __shared__ float  red[128];
    __shared__ float  gsh;

    const int b = blockIdx.x;
    const int t = threadIdx.x;
    const int w = t >> 6;
    const int l = t & 63;

    if (t < NNEI) conn_s[t] = *(const int4*)(conn + ((size_t)b * NNEI + t) * 4);

    const bool act = (l < 50);
    const int  d0  = 2 * l;
    float bias0 = 0.f, bias1 = 0.f, aw0 = 0.f, aw1 = 0.f;
    if (act) {
        bias0 = gcn_w_bias[d0]     + gcn_b[d0];
        bias1 = gcn_w_bias[d0 + 1] + gcn_b[d0 + 1];
        aw0   = attn_w[d0];
        aw1   = attn_w[d0 + 1];
    }
    const float abias = attn_bias[0];
    __syncthreads();

    // Wave w handles n = w + 16*j + 64*i  (j = 0..3 unrolled per iteration)
    for (int base = w; base < NNEI; base += 64) {
        uint32_t L[4][3];
        #pragma unroll
        for (int j = 0; j < 4; ++j) {
            const int nj = base + 16 * j;
            const int4 c = conn_s[(nj < NNEI) ? nj : 0];
            if (act) {
                L[j][0] = *(const uint32_t*)(P + (size_t)c.y * 300 +       d0);
                L[j][1] = *(const uint32_t*)(P + (size_t)c.z * 300 + 100 + d0);
                L[j][2] = *(const uint32_t*)(P + (size_t)c.w * 300 + 200 + d0);
            }
        }
        #pragma unroll
        for (int j = 0; j < 4; ++j) {
            const int nj = base + 16 * j;
            if (nj >= NNEI) break;                 // wave-uniform
            float p = 0.f;
            if (act) {
                bf2u a0, a1, a2;
                a0.u = L[j][0]; a1.u = L[j][1]; a2.u = L[j][2];
                float v0 = (float)a0.h[0] + (float)a1.h[0] + (float)a2.h[0] + bias0;
                float v1 = (float)a0.h[1] + (float)a1.h[1] + (float)a2.h[1] + bias1;
                v0 = v0 > 0.f ? v0 : 0.01f * v0;
                v1 = v1 > 0.f ? v1 : 0.01f * v1;
                bf2u o; o.h[0] = (__bf16)v0; o.h[1] = (__bf16)v1;
                *(uint32_t*)&out_s[nj][d0] = o.u;
                p = v0 * aw0 + v1 * aw1;
            }
            #pragma unroll
            for (int off = 32; off > 0; off >>= 1) p += __shfl_down(p, off);
            if (l == 0) logits[nj] = p + abias;
        }
    }
    __syncthreads();

    // softmax over all 200 neighbors (reference ignores num_neighbors)
    if (w == 0) {
        float vals[4];
        float mx = -1e30f;
        #pragma unroll
        for (int j = 0; j < 4; ++j) {
            const int n = l + 64 * j;
            vals[j] = (n < NNEI) ? logits[n] : -1e30f;
            mx = fmaxf(mx, vals[j]);
        }
        #pragma unroll
        for (int off = 32; off > 0; off >>= 1) mx = fmaxf(mx, __shfl_xor(mx, off));
        float sum = 0.f;
        #pragma unroll
        for (int j = 0; j < 4; ++j) {
            const int n = l + 64 * j;
            if (n < NNEI) { const float e = __expf(vals[j] - mx); wgt[n] = e; sum += e; }
        }
        #pragma unroll
        for (int off = 32; off > 0; off >>= 1) sum += __shfl_xor(sum, off);
        const float inv = 1.f / sum;
        #pragma unroll
        for (int j = 0; j < 4; ++j) {
            const int n = l + 64 * j;
            if (n < NNEI) wgt[n] *= inv;
        }
    }
    __syncthreads();

    // out_attn[d] = sum_n wgt[n]*out_s[n][d] — 8 groups of 128 thr, 25 n each
    {
        const int g  = t >> 7;
        const int dd = t & 127;
        if (dd < D_EMB) {
            float pa = 0.f;
            const int n0 = g * 25;
            #pragma unroll 5
            for (int n = n0; n < n0 + 25; ++n) pa += wgt[n] * (float)out_s[n][dd];
            part[g][dd] = pa;
        }
    }
    __syncthreads();

    float accd = 0.f;
    if (t < D_EMB) {
        #pragma unroll
        for (int g = 0; g < 8; ++g) accd += part[g][t];
        red[t] = accd * gate_w[t];
    } else if (t < 128) {
        red[t] = 0.f;
    }
    __syncthreads();

    if (w == 0) {
        float r = red[l] + red[l + 64];
        #pragma unroll
        for (int off = 32; off > 0; off >>= 1) r += __shfl_xor(r, off);
        if (l == 0) gsh = 1.f / (1.f + __expf(-(r + gate_w_bias[0] + gate_b[0])));
    }
    __syncthreads();

    if (t < D_EMB) {
        const int self = conn_s[0].x;              // connections[b][0][0]
        const float se = emb[(size_t)self * D_EMB + t];
        const float g  = gsh;
        out[(size_t)b * D_EMB + t] = accd * g + se * (1.f - g);
    }
}

// Diagnostic: if workspace is too small, encode ws_size (in MB) in d_out[0].
__global__ void ws_diag(float* out, float ws_mb) { out[0] = ws_mb; }

extern "C" void kernel_launch(void* const* d_in, const int* in_sizes, int n_in,
                              void* d_out, int out_size, void* d_ws, size_t ws_size,
                              hipStream_t stream) {
    const int*   conn        = (const int*)d_in[0];
    // d_in[1] = num_neighbors — unused by the reference
    const float* emb         = (const float*)d_in[2];
    const float* gcn_w       = (const float*)d_in[3];
    const float* gcn_w_bias  = (const float*)d_in[4];
    const float* gcn_b       = (const float*)d_in[5];
    const float* attn_w      = (const float*)d_in[6];
    const float* attn_bias   = (const float*)d_in[7];
    const float* gate_w      = (const float*)d_in[8];
    const float* gate_w_bias = (const float*)d_in[9];
    const float* gate_b      = (const float*)d_in[10];
    float* out = (float*)d_out;

    const size_t P_bytes = (size_t)NSYM * 300 * 2;                 // 60,000,600
    const size_t Bp_off  = (P_bytes + 255) & ~(size_t)255;
    const size_t need    = Bp_off + (size_t)BP_ELEMS * 2;          // +64,000

    if (ws_size < need) {
        ws_diag<<<1, 1, 0, stream>>>(out, (float)(ws_size / 1.0e6));
        return;
    }

    __bf16* P  = (__bf16*)d_ws;
    __bf16* Bp = (__bf16*)((char*)d_ws + Bp_off);

    prep_bp<<<(BP_ELEMS + 255) / 256, 256, 0, stream>>>(gcn_w, Bp);
    gemm_P<<<(NSYM + 63) / 64, 256, 0, stream>>>(emb, Bp, P);
    gather_attn<<<BATCH, 1024, 0, stream>>>(conn, P, emb, gcn_w_bias, gcn_b,
                                            attn_w, attn_bias, gate_w, gate_w_bias,
                                            gate_b, out);
}

// Round 5
// 185.167 us; speedup vs baseline: 1.9009x; 1.0744x over previous
//
#include <hip/hip_runtime.h>
#include <stdint.h>

#define D_EMB 100
#define NSYM 100001           // NUM_SYMBOLS + 1 rows in symbol_emb
#define BATCH 2048
#define NNEI 200
#define OS_STRIDE 102         // padded out_s row (51 dwords, odd -> conflict-free)

#define BP_ELEMS   32000      // packed Bp: 20 tiles x (3ks x 4q x 16n x 8 + 16n x 4)
#define BP_KS3_OFF 30720      // start of the dense ks=3 region

typedef __bf16 bf16x8 __attribute__((ext_vector_type(8)));
typedef __bf16 bf16x4 __attribute__((ext_vector_type(4)));
typedef float  f32x4  __attribute__((ext_vector_type(4)));
// reduced-alignment vector types for 8-B-aligned global stores
typedef bf16x8 bf16x8_a8 __attribute__((aligned(8)));
typedef bf16x4 bf16x4_a8 __attribute__((aligned(8)));

union bf2u { uint32_t u; __bf16 h[2]; };

// col covered by (tile tau, A-row n): paired-tile permutation so that
// lane quad's acc(tile 2u) ++ acc(tile 2u+1) = 8 consecutive P-columns.
__host__ __device__ inline int colmap(int tau, int n) {
    return 32 * (tau >> 1) + 8 * (n >> 2) + 4 * (tau & 1) + (n & 3);
}

// ---------------------------------------------------------------------------
// Kernel 1: repack gcn_w (100 x 300 fp32) into packed fragment-ordered Bp.
// ---------------------------------------------------------------------------
__global__ __launch_bounds__(256) void prep_bp(const float* __restrict__ gcn_w,
                                               __bf16* __restrict__ Bp) {
    int idx = blockIdx.x * 256 + threadIdx.x;
    if (idx >= BP_ELEMS) return;
    int tau, n, k;
    if (idx < BP_KS3_OFF) {
        int j = idx & 7;
        n     = (idx >> 3) & 15;
        int z = idx >> 7;            // tau*12 + ks*4 + q
        tau   = z / 12;
        int r = z - tau * 12;
        int ks = r >> 2, q = r & 3;
        k = ks * 32 + q * 8 + j;
    } else {
        int i2 = idx - BP_KS3_OFF;
        int j  = i2 & 3;
        n      = (i2 >> 2) & 15;
        tau    = i2 >> 6;
        k      = 96 + j;
    }
    const int col = colmap(tau, n);
    float v = 0.0f;
    if (col < 300 && k < 100) {
        int c = col / 100, d = col % 100;
        v = gcn_w[d * 300 + c * 100 + k];
    }
    Bp[idx] = (__bf16)v;
}

// ---------------------------------------------------------------------------
// Kernel 2: P = symbol_emb @ W'^T -> (100001 x 300) bf16.  (unchanged from R3)
// ---------------------------------------------------------------------------
__global__ __launch_bounds__(256) void gemm_P(const float* __restrict__ emb,
                                              const __bf16* __restrict__ Bp,
                                              __bf16* __restrict__ P) {
    __shared__ __bf16 BpS[BP_ELEMS + 8];     // + 8-elem zero slot

    const int tid  = threadIdx.x;
    const int wave = tid >> 6;
    const int lane = tid & 63;
    const int n    = lane & 15;
    const int quad = lane >> 4;

    {   // stage packed Bp into LDS (64,000 B contiguous, coalesced)
        const uint4* __restrict__ src = (const uint4*)Bp;
        uint4* dst = (uint4*)BpS;
        for (int c = tid; c < BP_ELEMS / 8; c += 256)    // 4000 x 16 B
            dst[c] = src[c];
        if (tid < 8) BpS[BP_ELEMS + tid] = (__bf16)0.0f; // zero slot
    }

    const int sBase = blockIdx.x * 64 + wave * 16;
    const int s     = sBase + n;
    const int srow  = (s <= NSYM - 1) ? s : (NSYM - 1);  // clamp loads
    const float* rowp = emb + (size_t)srow * D_EMB;

    bf16x8 b[4];
    #pragma unroll
    for (int ks = 0; ks < 3; ++ks) {                     // k0 <= 88
        const int k0 = ks * 32 + quad * 8;
        const float4 x = *(const float4*)(rowp + k0);
        const float4 y = *(const float4*)(rowp + k0 + 4);
        bf16x8 v;
        v[0]=(__bf16)x.x; v[1]=(__bf16)x.y; v[2]=(__bf16)x.z; v[3]=(__bf16)x.w;
        v[4]=(__bf16)y.x; v[5]=(__bf16)y.y; v[6]=(__bf16)y.z; v[7]=(__bf16)y.w;
        b[ks] = v;
    }
    {   // ks = 3: only quad 0 / k 96..99 nonzero
        bf16x8 v;
        #pragma unroll
        for (int i = 0; i < 8; ++i) v[i] = (__bf16)0.0f;
        if (quad == 0) {
            const float4 x = *(const float4*)(rowp + 96);
            v[0]=(__bf16)x.x; v[1]=(__bf16)x.y; v[2]=(__bf16)x.z; v[3]=(__bf16)x.w;
        }
        b[3] = v;
    }

    __syncthreads();

    const bool wr = (s <= NSYM - 1);
    __bf16* __restrict__ prow = P + (size_t)s * 300;

    for (int u = 0; u < 10; ++u) {
        const int t0 = 2 * u, t1 = t0 + 1;

        bf16x8 a0[4], a1[4];
        #pragma unroll
        for (int ks = 0; ks < 3; ++ks) {
            a0[ks] = *(const bf16x8*)&BpS[((t0 * 12 + ks * 4 + quad) * 16 + n) * 8];
            a1[ks] = *(const bf16x8*)&BpS[((t1 * 12 + ks * 4 + quad) * 16 + n) * 8];
        }
        {   // ks = 3: quad 0 reads dense 4-elem chunk; others read zero slot
            const int o0 = (quad == 0) ? (BP_KS3_OFF + (t0 * 16 + n) * 4) : BP_ELEMS;
            const int o1 = (quad == 0) ? (BP_KS3_OFF + (t1 * 16 + n) * 4) : BP_ELEMS;
            const bf16x4 w0 = *(const bf16x4*)&BpS[o0];
            const bf16x4 w1 = *(const bf16x4*)&BpS[o1];
            bf16x8 v0, v1;
            #pragma unroll
            for (int i = 0; i < 4; ++i) {
                v0[i] = w0[i]; v1[i] = w1[i];
                v0[i + 4] = (__bf16)0.0f; v1[i + 4] = (__bf16)0.0f;
            }
            a0[3] = v0; a1[3] = v1;
        }

        f32x4 acc0 = {0.f, 0.f, 0.f, 0.f};
        f32x4 acc1 = {0.f, 0.f, 0.f, 0.f};
        #pragma unroll
        for (int ks = 0; ks < 4; ++ks) {
            acc0 = __builtin_amdgcn_mfma_f32_16x16x32_bf16(a0[ks], b[ks], acc0, 0, 0, 0);
            acc1 = __builtin_amdgcn_mfma_f32_16x16x32_bf16(a1[ks], b[ks], acc1, 0, 0, 0);
        }

        if (wr) {
            const int colBase = 32 * u + 8 * quad;
            if (colBase + 8 <= 300) {
                bf16x8_a8 o;
                o[0]=(__bf16)acc0[0]; o[1]=(__bf16)acc0[1];
                o[2]=(__bf16)acc0[2]; o[3]=(__bf16)acc0[3];
                o[4]=(__bf16)acc1[0]; o[5]=(__bf16)acc1[1];
                o[6]=(__bf16)acc1[2]; o[7]=(__bf16)acc1[3];
                *(bf16x8_a8*)(prow + colBase) = o;
            } else if (colBase + 4 <= 300) {           // u=9, quad=1: 296..299
                bf16x4_a8 o;
                o[0]=(__bf16)acc0[0]; o[1]=(__bf16)acc0[1];
                o[2]=(__bf16)acc0[2]; o[3]=(__bf16)acc0[3];
                *(bf16x4_a8*)(prow + colBase) = o;
            }
        }
    }
}

// ---------------------------------------------------------------------------
// Kernel 3: per-batch fused gather + leaky-relu + attention softmax + gate.
// 1024 thr (16 waves) per batch, 2 blocks/CU. Phase 1 = pure gather with
// 8-neighbor unroll (24 loads in flight, NO per-neighbor reduction).
// Phase 1b computes logits from LDS (1 thread per neighbor). Then softmax,
// weighted sum, gate.
// ---------------------------------------------------------------------------
__global__ __launch_bounds__(1024, 8) void gather_attn(
        const int*    __restrict__ conn,        // (2048, 200, 4) int32
        const __bf16* __restrict__ P,           // (100001, 300) bf16
        const float*  __restrict__ emb,         // (100001, 100) fp32
        const float*  __restrict__ gcn_w_bias,
        const float*  __restrict__ gcn_b,
        const float*  __restrict__ attn_w,      // (100,)
        const float*  __restrict__ attn_bias,   // (1,)
        const float*  __restrict__ gate_w,      // (100,)
        const float*  __restrict__ gate_w_bias, // (1,)
        const float*  __restrict__ gate_b,      // (1,)
        float* __restrict__ out) {

    __shared__ __bf16 out_s[NNEI][OS_STRIDE];  // 40,800 B (padded rows)
    __shared__ int4   conn_s[NNEI];            //  3,200 B
    __shared__ float  logits[NNEI];
    __shared__ float  wgt[NNEI];
    __shared__ float2 aw_s[50];                //    400 B
    __shared__ float  part[8][D_EMB];
    __shared__ float  red[128];
    __shared__ float  gsh;

    const int b = blockIdx.x;
    const int t = threadIdx.x;
    const int w = t >> 6;
    const int l = t & 63;

    if (t < NNEI) conn_s[t] = *(const int4*)(conn + ((size_t)b * NNEI + t) * 4);
    if (t < 50)   aw_s[t] = make_float2(attn_w[2 * t], attn_w[2 * t + 1]);

    const bool act = (l < 50);
    const int  d0  = 2 * l;
    float bias0 = 0.f, bias1 = 0.f;
    if (act) {
        bias0 = gcn_w_bias[d0]     + gcn_b[d0];
        bias1 = gcn_w_bias[d0 + 1] + gcn_b[d0 + 1];
    }
    const float abias = attn_bias[0];
    __syncthreads();

    // ---- Phase 1: pure gather. Wave w covers n = w + 16j + 128*half. ----
    #pragma unroll
    for (int half = 0; half < 2; ++half) {
        const int b0 = w + half * 128;
        uint32_t L[8][3];
        #pragma unroll
        for (int j = 0; j < 8; ++j) {
            const int nj = b0 + 16 * j;
            if (act && nj < NNEI) {
                const int4 c = conn_s[nj];
                L[j][0] = *(const uint32_t*)(P + (size_t)c.y * 300 +       d0);
                L[j][1] = *(const uint32_t*)(P + (size_t)c.z * 300 + 100 + d0);
                L[j][2] = *(const uint32_t*)(P + (size_t)c.w * 300 + 200 + d0);
            }
        }
        #pragma unroll
        for (int j = 0; j < 8; ++j) {
            const int nj = b0 + 16 * j;
            if (act && nj < NNEI) {
                bf2u a0, a1, a2;
                a0.u = L[j][0]; a1.u = L[j][1]; a2.u = L[j][2];
                float v0 = (float)a0.h[0] + (float)a1.h[0] + (float)a2.h[0] + bias0;
                float v1 = (float)a0.h[1] + (float)a1.h[1] + (float)a2.h[1] + bias1;
                v0 = v0 > 0.f ? v0 : 0.01f * v0;
                v1 = v1 > 0.f ? v1 : 0.01f * v1;
                bf2u o; o.h[0] = (__bf16)v0; o.h[1] = (__bf16)v1;
                *(uint32_t*)&out_s[nj][d0] = o.u;
            }
        }
    }
    __syncthreads();

    // ---- Phase 1b: logits[n] = dot(out_s[n], attn_w) + abias ----
    if (t < NNEI) {
        const __bf16* row = &out_s[t][0];
        float pA = 0.f, pB = 0.f;
        #pragma unroll 5
        for (int j = 0; j < 50; j += 2) {
            bf2u v0; v0.u = *(const uint32_t*)(row + 2 * j);
            bf2u v1; v1.u = *(const uint32_t*)(row + 2 * j + 2);
            const float2 w0 = aw_s[j];
            const float2 w1 = aw_s[j + 1];
            pA += (float)v0.h[0] * w0.x + (float)v0.h[1] * w0.y;
            pB += (float)v1.h[0] * w1.x + (float)v1.h[1] * w1.y;
        }
        logits[t] = pA + pB + abias;
    }
    __syncthreads();

    // ---- softmax over all 200 neighbors ----
    if (w == 0) {
        float vals[4];
        float mx = -1e30f;
        #pragma unroll
        for (int j = 0; j < 4; ++j) {
            const int n = l + 64 * j;
            vals[j] = (n < NNEI) ? logits[n] : -1e30f;
            mx = fmaxf(mx, vals[j]);
        }
        #pragma unroll
        for (int off = 32; off > 0; off >>= 1) mx = fmaxf(mx, __shfl_xor(mx, off));
        float sum = 0.f;
        #pragma unroll
        for (int j = 0; j < 4; ++j) {
            const int n = l + 64 * j;
            if (n < NNEI) { const float e = __expf(vals[j] - mx); wgt[n] = e; sum += e; }
        }
        #pragma unroll
        for (int off = 32; off > 0; off >>= 1) sum += __shfl_xor(sum, off);
        const float inv = 1.f / sum;
        #pragma unroll
        for (int j = 0; j < 4; ++j) {
            const int n = l + 64 * j;
            if (n < NNEI) wgt[n] *= inv;
        }
    }
    __syncthreads();

    // ---- weighted sum: 8 groups of 128 thr, 25 neighbors each ----
    {
        const int g  = t >> 7;
        const int dd = t & 127;
        if (dd < D_EMB) {
            float pa = 0.f;
            const int n0 = g * 25;
            #pragma unroll 5
            for (int n = n0; n < n0 + 25; ++n) pa += wgt[n] * (float)out_s[n][dd];
            part[g][dd] = pa;
        }
    }
    __syncthreads();

    float accd = 0.f;
    if (t < D_EMB) {
        #pragma unroll
        for (int g = 0; g < 8; ++g) accd += part[g][t];
        red[t] = accd * gate_w[t];
    } else if (t < 128) {
        red[t] = 0.f;
    }
    __syncthreads();

    if (w == 0) {
        float r = red[l] + red[l + 64];
        #pragma unroll
        for (int off = 32; off > 0; off >>= 1) r += __shfl_xor(r, off);
        if (l == 0) gsh = 1.f / (1.f + __expf(-(r + gate_w_bias[0] + gate_b[0])));
    }
    __syncthreads();

    if (t < D_EMB) {
        const int self = conn_s[0].x;              // connections[b][0][0]
        const float se = emb[(size_t)self * D_EMB + t];
        const float g  = gsh;
        out[(size_t)b * D_EMB + t] = accd * g + se * (1.f - g);
    }
}

// Diagnostic: if workspace is too small, encode ws_size (in MB) in d_out[0].
__global__ void ws_diag(float* out, float ws_mb) { out[0] = ws_mb; }

extern "C" void kernel_launch(void* const* d_in, const int* in_sizes, int n_in,
                              void* d_out, int out_size, void* d_ws, size_t ws_size,
                              hipStream_t stream) {
    const int*   conn        = (const int*)d_in[0];
    // d_in[1] = num_neighbors — unused by the reference
    const float* emb         = (const float*)d_in[2];
    const float* gcn_w       = (const float*)d_in[3];
    const float* gcn_w_bias  = (const float*)d_in[4];
    const float* gcn_b       = (const float*)d_in[5];
    const float* attn_w      = (const float*)d_in[6];
    const float* attn_bias   = (const float*)d_in[7];
    const float* gate_w      = (const float*)d_in[8];
    const float* gate_w_bias = (const float*)d_in[9];
    const float* gate_b      = (const float*)d_in[10];
    float* out = (float*)d_out;

    const size_t P_bytes = (size_t)NSYM * 300 * 2;                 // 60,000,600
    const size_t Bp_off  = (P_bytes + 255) & ~(size_t)255;
    const size_t need    = Bp_off + (size_t)BP_ELEMS * 2;          // +64,000

    if (ws_size < need) {
        ws_diag<<<1, 1, 0, stream>>>(out, (float)(ws_size / 1.0e6));
        return;
    }

    __bf16* P  = (__bf16*)d_ws;
    __bf16* Bp = (__bf16*)((char*)d_ws + Bp_off);

    prep_bp<<<(BP_ELEMS + 255) / 256, 256, 0, stream>>>(gcn_w, Bp);
    gemm_P<<<(NSYM + 63) / 64, 256, 0, stream>>>(emb, Bp, P);
    gather_attn<<<BATCH, 1024, 0, stream>>>(conn, P, emb, gcn_w_bias, gcn_b,
                                            attn_w, attn_bias, gate_w, gate_w_bias,
                                            gate_b, out);
}

// Round 6
// 155.677 us; speedup vs baseline: 2.2610x; 1.1894x over previous
//
#include <hip/hip_runtime.h>
#include <stdint.h>

#define D_EMB 100
#define NSYM 100001           // NUM_SYMBOLS + 1 rows in symbol_emb
#define BATCH 2048
#define NNEI 200
#define OS_STRIDE 102         // padded out_s row (51 dwords, odd -> conflict-free)
#define P_STRIDE 304          // fp8 P row stride in BYTES (8-B aligned rows)
#define FP8_SCALE 256.0f
#define FP8_INV   0.00390625f // 1/256

#define BP_ELEMS   32000      // packed Bp: 20 tiles x (3ks x 4q x 16n x 8 + 16n x 4)
#define BP_KS3_OFF 30720      // start of the dense ks=3 region

typedef __bf16 bf16x8 __attribute__((ext_vector_type(8)));
typedef __bf16 bf16x4 __attribute__((ext_vector_type(4)));
typedef float  f32x4  __attribute__((ext_vector_type(4)));
typedef float  f32x2  __attribute__((ext_vector_type(2)));

union bf2u { uint32_t u; __bf16 h[2]; };

// col covered by (tile tau, A-row n): paired-tile permutation so that
// lane quad's acc(tile 2u) ++ acc(tile 2u+1) = 8 consecutive P-columns.
__host__ __device__ inline int colmap(int tau, int n) {
    return 32 * (tau >> 1) + 8 * (n >> 2) + 4 * (tau & 1) + (n & 3);
}

// ---------------------------------------------------------------------------
// Kernel 1: repack gcn_w (100 x 300 fp32) into packed fragment-ordered Bp.
// ---------------------------------------------------------------------------
__global__ __launch_bounds__(256) void prep_bp(const float* __restrict__ gcn_w,
                                               __bf16* __restrict__ Bp) {
    int idx = blockIdx.x * 256 + threadIdx.x;
    if (idx >= BP_ELEMS) return;
    int tau, n, k;
    if (idx < BP_KS3_OFF) {
        int j = idx & 7;
        n     = (idx >> 3) & 15;
        int z = idx >> 7;            // tau*12 + ks*4 + q
        tau   = z / 12;
        int r = z - tau * 12;
        int ks = r >> 2, q = r & 3;
        k = ks * 32 + q * 8 + j;
    } else {
        int i2 = idx - BP_KS3_OFF;
        int j  = i2 & 3;
        n      = (i2 >> 2) & 15;
        tau    = i2 >> 6;
        k      = 96 + j;
    }
    const int col = colmap(tau, n);
    float v = 0.0f;
    if (col < 300 && k < 100) {
        int c = col / 100, d = col % 100;
        v = gcn_w[d * 300 + c * 100 + k];
    }
    Bp[idx] = (__bf16)v;
}

// ---------------------------------------------------------------------------
// helper: load one symbol row's emb fragment (B operand, K=128 w/ pad)
// ---------------------------------------------------------------------------
__device__ inline void load_bfrag(const float* __restrict__ rowp, int quad,
                                  bf16x8 b[4]) {
    #pragma unroll
    for (int ks = 0; ks < 3; ++ks) {                     // k0 <= 88
        const int k0 = ks * 32 + quad * 8;
        const float4 x = *(const float4*)(rowp + k0);
        const float4 y = *(const float4*)(rowp + k0 + 4);
        bf16x8 v;
        v[0]=(__bf16)x.x; v[1]=(__bf16)x.y; v[2]=(__bf16)x.z; v[3]=(__bf16)x.w;
        v[4]=(__bf16)y.x; v[5]=(__bf16)y.y; v[6]=(__bf16)y.z; v[7]=(__bf16)y.w;
        b[ks] = v;
    }
    bf16x8 v;
    #pragma unroll
    for (int i = 0; i < 8; ++i) v[i] = (__bf16)0.0f;
    if (quad == 0) {
        const float4 x = *(const float4*)(rowp + 96);
        v[0]=(__bf16)x.x; v[1]=(__bf16)x.y; v[2]=(__bf16)x.z; v[3]=(__bf16)x.w;
    }
    b[3] = v;
}

__device__ inline uint32_t pack_fp8x4(float a, float b, float c, float d) {
    uint32_t w = (uint32_t)__builtin_amdgcn_cvt_pk_fp8_f32(a, b, 0, false);
    w = (uint32_t)__builtin_amdgcn_cvt_pk_fp8_f32(c, d, (int)w, true);
    return w;
}

// ---------------------------------------------------------------------------
// Kernel 2: P8 = fp8_e4m3( symbol_emb @ W'^T * 256 ) -> (100001 x 304B).
// 512 thr = 8 waves, 32 symbols per wave (a-frags shared across 2 sym-tiles),
// 256 symbols per block, 391 blocks (all co-resident at 2 blocks/CU,
// 16 waves/CU). Bp staged once per block in LDS (fragment-ordered,
// conflict-free b128 reads).
// ---------------------------------------------------------------------------
__global__ __launch_bounds__(512, 4) void gemm_P(const float* __restrict__ emb,
                                                 const __bf16* __restrict__ Bp,
                                                 uint8_t* __restrict__ P8) {
    __shared__ __bf16 BpS[BP_ELEMS + 8];     // + 8-elem zero slot

    const int tid  = threadIdx.x;
    const int wave = tid >> 6;               // 0..7
    const int lane = tid & 63;
    const int n    = lane & 15;
    const int quad = lane >> 4;

    {   // stage packed Bp into LDS (64,000 B contiguous, coalesced)
        const uint4* __restrict__ src = (const uint4*)Bp;
        uint4* dst = (uint4*)BpS;
        for (int c = tid; c < BP_ELEMS / 8; c += 512)    // 4000 x 16 B
            dst[c] = src[c];
        if (tid < 8) BpS[BP_ELEMS + tid] = (__bf16)0.0f; // zero slot
    }

    const int sA = blockIdx.x * 256 + wave * 32 + n;     // sym-tile A
    const int sB = sA + 16;                              // sym-tile B
    const int rA = (sA <= NSYM - 1) ? sA : (NSYM - 1);
    const int rB = (sB <= NSYM - 1) ? sB : (NSYM - 1);

    bf16x8 bA[4], bB[4];
    load_bfrag(emb + (size_t)rA * D_EMB, quad, bA);
    load_bfrag(emb + (size_t)rB * D_EMB, quad, bB);

    __syncthreads();

    const bool wrA = (sA <= NSYM - 1);
    const bool wrB = (sB <= NSYM - 1);
    uint8_t* __restrict__ prA = P8 + (size_t)sA * P_STRIDE;
    uint8_t* __restrict__ prB = P8 + (size_t)sB * P_STRIDE;

    for (int u = 0; u < 10; ++u) {
        const int t0 = 2 * u, t1 = t0 + 1;

        bf16x8 a0[4], a1[4];
        #pragma unroll
        for (int ks = 0; ks < 3; ++ks) {
            a0[ks] = *(const bf16x8*)&BpS[((t0 * 12 + ks * 4 + quad) * 16 + n) * 8];
            a1[ks] = *(const bf16x8*)&BpS[((t1 * 12 + ks * 4 + quad) * 16 + n) * 8];
        }
        {   // ks = 3: quad 0 reads dense 4-elem chunk; others read zero slot
            const int o0 = (quad == 0) ? (BP_KS3_OFF + (t0 * 16 + n) * 4) : BP_ELEMS;
            const int o1 = (quad == 0) ? (BP_KS3_OFF + (t1 * 16 + n) * 4) : BP_ELEMS;
            const bf16x4 w0 = *(const bf16x4*)&BpS[o0];
            const bf16x4 w1 = *(const bf16x4*)&BpS[o1];
            bf16x8 v0, v1;
            #pragma unroll
            for (int i = 0; i < 4; ++i) {
                v0[i] = w0[i]; v1[i] = w1[i];
                v0[i + 4] = (__bf16)0.0f; v1[i + 4] = (__bf16)0.0f;
            }
            a0[3] = v0; a1[3] = v1;
        }

        f32x4 aA0 = {0.f,0.f,0.f,0.f}, aA1 = {0.f,0.f,0.f,0.f};
        f32x4 aB0 = {0.f,0.f,0.f,0.f}, aB1 = {0.f,0.f,0.f,0.f};
        #pragma unroll
        for (int ks = 0; ks < 4; ++ks) {
            aA0 = __builtin_amdgcn_mfma_f32_16x16x32_bf16(a0[ks], bA[ks], aA0, 0, 0, 0);
            aA1 = __builtin_amdgcn_mfma_f32_16x16x32_bf16(a1[ks], bA[ks], aA1, 0, 0, 0);
            aB0 = __builtin_amdgcn_mfma_f32_16x16x32_bf16(a0[ks], bB[ks], aB0, 0, 0, 0);
            aB1 = __builtin_amdgcn_mfma_f32_16x16x32_bf16(a1[ks], bB[ks], aB1, 0, 0, 0);
        }

        // lane (n, quad): symbol sA/sB, cols 32u + 8q + {0..7} (acc0 | acc1)
        const int colBase = 32 * u + 8 * quad;
        if (colBase + 8 <= 300) {
            if (wrA) {
                uint2 o;
                o.x = pack_fp8x4(aA0[0]*FP8_SCALE, aA0[1]*FP8_SCALE,
                                 aA0[2]*FP8_SCALE, aA0[3]*FP8_SCALE);
                o.y = pack_fp8x4(aA1[0]*FP8_SCALE, aA1[1]*FP8_SCALE,
                                 aA1[2]*FP8_SCALE, aA1[3]*FP8_SCALE);
                *(uint2*)(prA + colBase) = o;
            }
            if (wrB) {
                uint2 o;
                o.x = pack_fp8x4(aB0[0]*FP8_SCALE, aB0[1]*FP8_SCALE,
                                 aB0[2]*FP8_SCALE, aB0[3]*FP8_SCALE);
                o.y = pack_fp8x4(aB1[0]*FP8_SCALE, aB1[1]*FP8_SCALE,
                                 aB1[2]*FP8_SCALE, aB1[3]*FP8_SCALE);
                *(uint2*)(prB + colBase) = o;
            }
        } else if (colBase + 4 <= 300) {                 // u=9, q=1: 296..299
            if (wrA)
                *(uint32_t*)(prA + colBase) =
                    pack_fp8x4(aA0[0]*FP8_SCALE, aA0[1]*FP8_SCALE,
                               aA0[2]*FP8_SCALE, aA0[3]*FP8_SCALE);
            if (wrB)
                *(uint32_t*)(prB + colBase) =
                    pack_fp8x4(aB0[0]*FP8_SCALE, aB0[1]*FP8_SCALE,
                               aB0[2]*FP8_SCALE, aB0[3]*FP8_SCALE);
        }
    }
}

// ---------------------------------------------------------------------------
// Kernel 3: per-batch fused gather + leaky-relu + attention softmax + gate.
// 1024 thr per batch, 2 blocks/CU. Phase 1 is a flat element-parallel loop:
// work item = (neighbor n, 4-dim chunk li), 5000 items, 3 fp8-dword loads
// each, no cross-lane ops. Phase 1b = logits (2 thr/neighbor), then softmax,
// weighted sum, gate.
// ---------------------------------------------------------------------------
__global__ __launch_bounds__(1024, 8) void gather_attn(
        const int*     __restrict__ conn,        // (2048, 200, 4) int32
        const uint8_t* __restrict__ P8,          // (100001, 304B) fp8 e4m3
        const float*   __restrict__ emb,         // (100001, 100) fp32
        const float*   __restrict__ gcn_w_bias,
        const float*   __restrict__ gcn_b,
        const float*   __restrict__ attn_w,      // (100,)
        const float*   __restrict__ attn_bias,   // (1,)
        const float*   __restrict__ gate_w,      // (100,)
        const float*   __restrict__ gate_w_bias, // (1,)
        const float*   __restrict__ gate_b,      // (1,)
        float* __restrict__ out) {

    __shared__ __bf16 out_s[NNEI][OS_STRIDE];  // 40,800 B (padded rows)
    __shared__ int4   conn_s[NNEI];            //  3,200 B
    __shared__ float  logits[NNEI];
    __shared__ float  logit2[NNEI][2];
    __shared__ float  wgt[NNEI];
    __shared__ float2 aw_s[50];
    __shared__ float4 bias4_s[25];
    __shared__ float  part[8][D_EMB];
    __shared__ float  red[128];
    __shared__ float  gsh;

    const int b = blockIdx.x;
    const int t = threadIdx.x;
    const int w = t >> 6;
    const int l = t & 63;

    if (t < NNEI) conn_s[t] = *(const int4*)(conn + ((size_t)b * NNEI + t) * 4);
    if (t < 50)   aw_s[t] = make_float2(attn_w[2 * t], attn_w[2 * t + 1]);
    if (t < 25)
        bias4_s[t] = make_float4(gcn_w_bias[4*t]   + gcn_b[4*t],
                                 gcn_w_bias[4*t+1] + gcn_b[4*t+1],
                                 gcn_w_bias[4*t+2] + gcn_b[4*t+2],
                                 gcn_w_bias[4*t+3] + gcn_b[4*t+3]);
    const float abias = attn_bias[0];
    __syncthreads();

    // ---- Phase 1: 5000 work items = 200 neighbors x 25 dword chunks ----
    #pragma unroll
    for (int i = 0; i < 5; ++i) {
        const int idx = t + 1024 * i;
        if (idx < NNEI * 25) {
            const int n  = idx / 25;
            const int li = idx - n * 25;
            const int4 c = conn_s[n];
            const uint32_t u0 = *(const uint32_t*)(P8 + (size_t)c.y * P_STRIDE +       li * 4);
            const uint32_t u1 = *(const uint32_t*)(P8 + (size_t)c.z * P_STRIDE + 100 + li * 4);
            const uint32_t u2 = *(const uint32_t*)(P8 + (size_t)c.w * P_STRIDE + 200 + li * 4);
            const f32x2 y0 = __builtin_amdgcn_cvt_pk_f32_fp8((int)u0, false);
            const f32x2 y1 = __builtin_amdgcn_cvt_pk_f32_fp8((int)u0, true);
            const f32x2 z0 = __builtin_amdgcn_cvt_pk_f32_fp8((int)u1, false);
            const f32x2 z1 = __builtin_amdgcn_cvt_pk_f32_fp8((int)u1, true);
            const f32x2 q0 = __builtin_amdgcn_cvt_pk_f32_fp8((int)u2, false);
            const f32x2 q1 = __builtin_amdgcn_cvt_pk_f32_fp8((int)u2, true);
            const float4 bb = bias4_s[li];
            float v0 = (y0[0] + z0[0] + q0[0]) * FP8_INV + bb.x;
            float v1 = (y0[1] + z0[1] + q0[1]) * FP8_INV + bb.y;
            float v2 = (y1[0] + z1[0] + q1[0]) * FP8_INV + bb.z;
            float v3 = (y1[1] + z1[1] + q1[1]) * FP8_INV + bb.w;
            v0 = v0 > 0.f ? v0 : 0.01f * v0;
            v1 = v1 > 0.f ? v1 : 0.01f * v1;
            v2 = v2 > 0.f ? v2 : 0.01f * v2;
            v3 = v3 > 0.f ? v3 : 0.01f * v3;
            bf2u o01; o01.h[0] = (__bf16)v0; o01.h[1] = (__bf16)v1;
            bf2u o23; o23.h[0] = (__bf16)v2; o23.h[1] = (__bf16)v3;
            *(uint32_t*)&out_s[n][4 * li]     = o01.u;
            *(uint32_t*)&out_s[n][4 * li + 2] = o23.u;
        }
    }
    __syncthreads();

    // ---- Phase 1b: logits, 2 threads per neighbor ----
    if (t < 2 * NNEI) {
        const int n = t >> 1, half = t & 1;
        const __bf16* row = &out_s[n][half * 50];
        float p = 0.f;
        #pragma unroll 5
        for (int j = 0; j < 25; ++j) {
            bf2u v; v.u = *(const uint32_t*)(row + 2 * j);
            const float2 ww = aw_s[half * 25 + j];
            p += (float)v.h[0] * ww.x + (float)v.h[1] * ww.y;
        }
        logit2[n][half] = p;
    }
    __syncthreads();
    if (t < NNEI) logits[t] = logit2[t][0] + logit2[t][1] + abias;
    __syncthreads();

    // ---- softmax over all 200 neighbors ----
    if (w == 0) {
        float vals[4];
        float mx = -1e30f;
        #pragma unroll
        for (int j = 0; j < 4; ++j) {
            const int n = l + 64 * j;
            vals[j] = (n < NNEI) ? logits[n] : -1e30f;
            mx = fmaxf(mx, vals[j]);
        }
        #pragma unroll
        for (int off = 32; off > 0; off >>= 1) mx = fmaxf(mx, __shfl_xor(mx, off));
        float sum = 0.f;
        #pragma unroll
        for (int j = 0; j < 4; ++j) {
            const int n = l + 64 * j;
            if (n < NNEI) { const float e = __expf(vals[j] - mx); wgt[n] = e; sum += e; }
        }
        #pragma unroll
        for (int off = 32; off > 0; off >>= 1) sum += __shfl_xor(sum, off);
        const float inv = 1.f / sum;
        #pragma unroll
        for (int j = 0; j < 4; ++j) {
            const int n = l + 64 * j;
            if (n < NNEI) wgt[n] *= inv;
        }
    }
    __syncthreads();

    // ---- weighted sum: 8 groups of 128 thr, 25 neighbors each ----
    {
        const int g  = t >> 7;
        const int dd = t & 127;
        if (dd < D_EMB) {
            float pa = 0.f;
            const int n0 = g * 25;
            #pragma unroll 5
            for (int n = n0; n < n0 + 25; ++n) pa += wgt[n] * (float)out_s[n][dd];
            part[g][dd] = pa;
        }
    }
    __syncthreads();

    float accd = 0.f;
    if (t < D_EMB) {
        #pragma unroll
        for (int g = 0; g < 8; ++g) accd += part[g][t];
        red[t] = accd * gate_w[t];
    } else if (t < 128) {
        red[t] = 0.f;
    }
    __syncthreads();

    if (w == 0) {
        float r = red[l] + red[l + 64];
        #pragma unroll
        for (int off = 32; off > 0; off >>= 1) r += __shfl_xor(r, off);
        if (l == 0) gsh = 1.f / (1.f + __expf(-(r + gate_w_bias[0] + gate_b[0])));
    }
    __syncthreads();

    if (t < D_EMB) {
        const int self = conn_s[0].x;              // connections[b][0][0]
        const float se = emb[(size_t)self * D_EMB + t];
        const float g  = gsh;
        out[(size_t)b * D_EMB + t] = accd * g + se * (1.f - g);
    }
}

// Diagnostic: if workspace is too small, encode ws_size (in MB) in d_out[0].
__global__ void ws_diag(float* out, float ws_mb) { out[0] = ws_mb; }

extern "C" void kernel_launch(void* const* d_in, const int* in_sizes, int n_in,
                              void* d_out, int out_size, void* d_ws, size_t ws_size,
                              hipStream_t stream) {
    const int*   conn        = (const int*)d_in[0];
    // d_in[1] = num_neighbors — unused by the reference
    const float* emb         = (const float*)d_in[2];
    const float* gcn_w       = (const float*)d_in[3];
    const float* gcn_w_bias  = (const float*)d_in[4];
    const float* gcn_b       = (const float*)d_in[5];
    const float* attn_w      = (const float*)d_in[6];
    const float* attn_bias   = (const float*)d_in[7];
    const float* gate_w      = (const float*)d_in[8];
    const float* gate_w_bias = (const float*)d_in[9];
    const float* gate_b      = (const float*)d_in[10];
    float* out = (float*)d_out;

    const size_t P_bytes = (size_t)NSYM * P_STRIDE;                // 30,400,304
    const size_t Bp_off  = (P_bytes + 255) & ~(size_t)255;
    const size_t need    = Bp_off + (size_t)BP_ELEMS * 2;          // +64,000

    if (ws_size < need) {
        ws_diag<<<1, 1, 0, stream>>>(out, (float)(ws_size / 1.0e6));
        return;
    }

    uint8_t* P8 = (uint8_t*)d_ws;
    __bf16*  Bp = (__bf16*)((char*)d_ws + Bp_off);

    prep_bp<<<(BP_ELEMS + 255) / 256, 256, 0, stream>>>(gcn_w, Bp);
    gemm_P<<<(NSYM + 255) / 256, 512, 0, stream>>>(emb, Bp, P8);
    gather_attn<<<BATCH, 1024, 0, stream>>>(conn, P8, emb, gcn_w_bias, gcn_b,
                                            attn_w, attn_bias, gate_w, gate_w_bias,
                                            gate_b, out);
}